// Round 1
// baseline (761.095 us; speedup 1.0000x reference)
//
#include <hip/hip_runtime.h>
#include <hip/hip_bf16.h>

#define N_NODES 100000
#define N_EDGES 1000000
#define EMB 64
#define HID 64
#define N_GRAPHS 2048

// ---------------- embed: h[i][:] = emb[x[i]][:] ----------------
__global__ __launch_bounds__(256) void embed_kernel(
    const int* __restrict__ x, const float* __restrict__ emb,
    float* __restrict__ h)
{
    int tid = blockIdx.x * 256 + threadIdx.x;        // N_NODES*16 threads
    if (tid >= N_NODES * 16) return;
    int node = tid >> 4, part = tid & 15;
    int v = x[node];
    float4 val = ((const float4*)emb)[v * 16 + part];
    ((float4*)h)[node * 16 + part] = val;
}

// ---------------- degree histogram ----------------
__global__ __launch_bounds__(256) void deg_kernel(
    const int* __restrict__ dst, int* __restrict__ deg)
{
    int e = blockIdx.x * 256 + threadIdx.x;
    if (e < N_EDGES) atomicAdd(&deg[dst[e]], 1);
}

// ---------------- block-scan bases (order-free CSR base assignment) ------
__global__ __launch_bounds__(256) void base_kernel(
    const int* __restrict__ deg, int* __restrict__ row_start,
    int* __restrict__ cursor, int* __restrict__ total)
{
    __shared__ int sdata[256];
    __shared__ int sbase;
    int t = threadIdx.x;
    int i = blockIdx.x * 256 + t;
    int v = (i < N_NODES) ? deg[i] : 0;
    sdata[t] = v;
    __syncthreads();
    for (int off = 1; off < 256; off <<= 1) {
        int tmp = (t >= off) ? sdata[t - off] : 0;
        __syncthreads();
        sdata[t] += tmp;
        __syncthreads();
    }
    if (t == 255) sbase = atomicAdd(total, sdata[255]);
    __syncthreads();
    if (i < N_NODES) {
        int b = sbase + sdata[t] - v;   // exclusive prefix + block base
        row_start[i] = b;
        cursor[i] = b;
    }
}

// ---------------- CSR fill ----------------
__global__ __launch_bounds__(256) void fill_kernel(
    const int* __restrict__ src, const int* __restrict__ dst,
    int* __restrict__ cursor, int* __restrict__ col)
{
    int e = blockIdx.x * 256 + threadIdx.x;
    if (e < N_EDGES) {
        int p = atomicAdd(&cursor[dst[e]], 1);
        col[p] = src[e];
    }
}

// ---------------- fused SAGE layer: mean-agg + (mean@Wl + b + h@Wr), relu -
// one wave per node; lane = output feature
__global__ __launch_bounds__(256) void sage_layer(
    const float* __restrict__ h_in, float* __restrict__ h_out,
    const int* __restrict__ row_start, const int* __restrict__ deg,
    const int* __restrict__ col,
    const float* __restrict__ Wl, const float* __restrict__ Wr,
    const float* __restrict__ bias)
{
    __shared__ float2 w[HID * HID];   // (Wl[d][k], Wr[d][k]) interleaved, 32 KB
    __shared__ float bsh[HID];
    int t = threadIdx.x;
    for (int idx = t; idx < HID * HID; idx += 256)
        w[idx] = make_float2(Wl[idx], Wr[idx]);
    if (t < HID) bsh[t] = bias[t];
    __syncthreads();

    int wave = t >> 6;
    int lane = t & 63;
    int node = blockIdx.x * 4 + wave;
    if (node >= N_NODES) return;

    int rs = row_start[node];
    int dg = deg[node];
    float sum = 0.f;
    for (int j = 0; j < dg; ++j) {
        int s = col[rs + j];               // wave-uniform load
        sum += h_in[s * 64 + lane];        // coalesced 256B per neighbor
    }
    float mean = sum / fmaxf((float)dg, 1.0f);
    float self = h_in[node * 64 + lane];

    float acc = bsh[lane];
#pragma unroll
    for (int d = 0; d < HID; ++d) {
        float m = __int_as_float(__builtin_amdgcn_readlane(__float_as_int(mean), d));
        float s = __int_as_float(__builtin_amdgcn_readlane(__float_as_int(self), d));
        float2 wv = w[d * 64 + lane];
        acc += m * wv.x + s * wv.y;
    }
    acc = fmaxf(acc, 0.f);                 // relu (both layers)
    h_out[node * 64 + lane] = acc;
}

// ---------------- graph boundary detection (batch is sorted) -------------
__global__ __launch_bounds__(256) void gptr_kernel(
    const int* __restrict__ batch, int* __restrict__ gstart)
{
    int i = blockIdx.x * 256 + threadIdx.x;
    if (i >= N_NODES) return;
    int b = batch[i];
    int bp = (i == 0) ? -1 : batch[i - 1];
    for (int g = bp + 1; g <= b; ++g) gstart[g] = i;
    if (i == N_NODES - 1)
        for (int g = b + 1; g <= N_GRAPHS; ++g) gstart[g] = N_NODES;
}

// ---------------- mean pool + output matmul (one wave per graph) ---------
__global__ __launch_bounds__(256) void pool_kernel(
    const float* __restrict__ h, const int* __restrict__ gstart,
    const float* __restrict__ Wout, const float* __restrict__ bout,
    float* __restrict__ out)
{
    int t = threadIdx.x;
    int wave = t >> 6;
    int lane = t & 63;
    int g = blockIdx.x * 4 + wave;
    if (g >= N_GRAPHS) return;
    int s = gstart[g], e = gstart[g + 1];
    float sum = 0.f;
    for (int i = s; i < e; ++i) sum += h[i * 64 + lane];
    float pooled = sum / fmaxf((float)(e - s), 1.0f);
    float r0 = pooled * Wout[lane * 2 + 0];
    float r1 = pooled * Wout[lane * 2 + 1];
#pragma unroll
    for (int off = 32; off > 0; off >>= 1) {
        r0 += __shfl_down(r0, off, 64);
        r1 += __shfl_down(r1, off, 64);
    }
    if (lane == 0) {
        out[g * 2 + 0] = r0 + bout[0];
        out[g * 2 + 1] = r1 + bout[1];
    }
}

extern "C" void kernel_launch(void* const* d_in, const int* in_sizes, int n_in,
                              void* d_out, int out_size, void* d_ws, size_t ws_size,
                              hipStream_t stream) {
    const int*   x    = (const int*)  d_in[0];
    const int*   ei   = (const int*)  d_in[1];   // [2, E] flat
    const int*   batch= (const int*)  d_in[2];
    const float* emb  = (const float*)d_in[3];
    const float* W1l  = (const float*)d_in[4];
    const float* b1   = (const float*)d_in[5];
    const float* W1r  = (const float*)d_in[6];
    const float* W2l  = (const float*)d_in[7];
    const float* b2   = (const float*)d_in[8];
    const float* W2r  = (const float*)d_in[9];
    const float* Wout = (const float*)d_in[10];
    const float* bout = (const float*)d_in[11];
    float* out = (float*)d_out;

    const int* src = ei;
    const int* dst = ei + N_EDGES;

    // workspace layout
    char* ws = (char*)d_ws;
    size_t off = 0;
    float* hA       = (float*)(ws + off); off += (size_t)N_NODES * 64 * 4;   // 25.6 MB
    float* hB       = (float*)(ws + off); off += (size_t)N_NODES * 64 * 4;   // 25.6 MB
    int*   deg      = (int*)  (ws + off); off += (size_t)N_NODES * 4;
    int*   rowst    = (int*)  (ws + off); off += (size_t)N_NODES * 4;
    int*   cursor   = (int*)  (ws + off); off += (size_t)N_NODES * 4;
    int*   col      = (int*)  (ws + off); off += (size_t)N_EDGES * 4;
    int*   gstart   = (int*)  (ws + off); off += (size_t)(N_GRAPHS + 1) * 4;
    int*   total    = (int*)  (ws + off); off += 16;

    // zero what must be zero (ws is poisoned 0xAA before every call)
    hipMemsetAsync(deg, 0, (size_t)N_NODES * 4, stream);
    hipMemsetAsync(total, 0, 16, stream);

    // embed
    embed_kernel<<<(N_NODES * 16 + 255) / 256, 256, 0, stream>>>(x, emb, hA);
    // CSR build
    deg_kernel<<<(N_EDGES + 255) / 256, 256, 0, stream>>>(dst, deg);
    base_kernel<<<(N_NODES + 255) / 256, 256, 0, stream>>>(deg, rowst, cursor, total);
    fill_kernel<<<(N_EDGES + 255) / 256, 256, 0, stream>>>(src, dst, cursor, col);
    // graph boundaries (independent of layers; do it here)
    gptr_kernel<<<(N_NODES + 255) / 256, 256, 0, stream>>>(batch, gstart);
    // layer 1: hA -> hB
    sage_layer<<<(N_NODES + 3) / 4, 256, 0, stream>>>(hA, hB, rowst, deg, col, W1l, W1r, b1);
    // layer 2: hB -> hA
    sage_layer<<<(N_NODES + 3) / 4, 256, 0, stream>>>(hB, hA, rowst, deg, col, W2l, W2r, b2);
    // pool + classify
    pool_kernel<<<(N_GRAPHS + 3) / 4, 256, 0, stream>>>(hA, gstart, Wout, bout, out);
}

// Round 2
// 444.800 us; speedup vs baseline: 1.7111x; 1.7111x over previous
//
#include <hip/hip_runtime.h>
#include <hip/hip_bf16.h>

#define N_NODES 100000
#define N_EDGES 1000000
#define EMB 64
#define HID 64
#define N_GRAPHS 2048
#define NODES_PER_WAVE 8
#define NODES_PER_BLOCK (4 * NODES_PER_WAVE)

#define BCAST(v, l) __int_as_float(__builtin_amdgcn_readlane(__float_as_int(v), (l)))

// ---------------- embed: h[i][:] = emb[x[i]][:] ----------------
__global__ __launch_bounds__(256) void embed_kernel(
    const int* __restrict__ x, const float* __restrict__ emb,
    float* __restrict__ h)
{
    int tid = blockIdx.x * 256 + threadIdx.x;        // N_NODES*16 threads
    if (tid >= N_NODES * 16) return;
    int node = tid >> 4, part = tid & 15;
    int v = x[node];
    float4 val = ((const float4*)emb)[v * 16 + part];
    ((float4*)h)[node * 16 + part] = val;
}

// ---------------- degree histogram ----------------
__global__ __launch_bounds__(256) void deg_kernel(
    const int* __restrict__ dst, int* __restrict__ deg)
{
    int e = blockIdx.x * 256 + threadIdx.x;
    if (e < N_EDGES) atomicAdd(&deg[dst[e]], 1);
}

// ------- block-scan bases (order-free CSR base assignment) + gstart ------
__global__ __launch_bounds__(256) void base_kernel(
    const int* __restrict__ deg, int* __restrict__ row_start,
    int* __restrict__ cursor, int* __restrict__ total,
    const int* __restrict__ batch, int* __restrict__ gstart)
{
    __shared__ int sdata[256];
    __shared__ int sbase;
    int t = threadIdx.x;
    int i = blockIdx.x * 256 + t;
    int v = (i < N_NODES) ? deg[i] : 0;
    sdata[t] = v;
    __syncthreads();
    for (int off = 1; off < 256; off <<= 1) {
        int tmp = (t >= off) ? sdata[t - off] : 0;
        __syncthreads();
        sdata[t] += tmp;
        __syncthreads();
    }
    if (t == 255) sbase = atomicAdd(total, sdata[255]);
    __syncthreads();
    if (i < N_NODES) {
        int b = sbase + sdata[t] - v;   // exclusive prefix + block base
        row_start[i] = b;
        cursor[i] = b;
        // graph boundary detection (batch is sorted)
        int bg = batch[i];
        int bp = (i == 0) ? -1 : batch[i - 1];
        for (int g = bp + 1; g <= bg; ++g) gstart[g] = i;
        if (i == N_NODES - 1)
            for (int g = bg + 1; g <= N_GRAPHS; ++g) gstart[g] = N_NODES;
    }
}

// ---------------- CSR fill ----------------
__global__ __launch_bounds__(256) void fill_kernel(
    const int* __restrict__ src, const int* __restrict__ dst,
    int* __restrict__ cursor, int* __restrict__ col)
{
    int e = blockIdx.x * 256 + threadIdx.x;
    if (e < N_EDGES) {
        int p = atomicAdd(&cursor[dst[e]], 1);
        col[p] = src[e];
    }
}

// ---- fused SAGE layer: mean-agg + (mean@Wl + b + self@Wr), relu ----
// one wave per node-group of NODES_PER_WAVE; lane = output feature
__global__ __launch_bounds__(256) void sage_layer(
    const float* __restrict__ h_in, float* __restrict__ h_out,
    const int* __restrict__ row_start, const int* __restrict__ deg,
    const int* __restrict__ col,
    const float* __restrict__ Wl, const float* __restrict__ Wr,
    const float* __restrict__ bias)
{
    __shared__ float2 w[HID * HID];   // (Wl[d][o], Wr[d][o]) interleaved, 32 KB
    __shared__ float bsh[HID];
    int t = threadIdx.x;
    // vectorized weight staging: 4 idx per thread per iter
    for (int idx = t * 4; idx < HID * HID; idx += 256 * 4) {
        float4 a = *(const float4*)(Wl + idx);
        float4 b = *(const float4*)(Wr + idx);
        w[idx + 0] = make_float2(a.x, b.x);
        w[idx + 1] = make_float2(a.y, b.y);
        w[idx + 2] = make_float2(a.z, b.z);
        w[idx + 3] = make_float2(a.w, b.w);
    }
    if (t < HID) bsh[t] = bias[t];
    __syncthreads();

    int wave = t >> 6;
    int lane = t & 63;
    int base_node = blockIdx.x * NODES_PER_BLOCK + wave * NODES_PER_WAVE;

    for (int i = 0; i < NODES_PER_WAVE; ++i) {
        int node = base_node + i;
        if (node >= N_NODES) return;

        int rs = row_start[node];
        int dg = deg[node];
        float self = h_in[node * 64 + lane];    // issue early

        // lane-parallel prefetch of neighbor indices (one coalesced load)
        int cidx = (lane < dg) ? col[rs + lane] : 0;
        int dgc = (dg < 64) ? dg : 64;

        float sum0 = 0.f, sum1 = 0.f, sum2 = 0.f, sum3 = 0.f;
        int j = 0;
        for (; j + 4 <= dgc; j += 4) {         // 4 gathers in flight
            int s0 = __builtin_amdgcn_readlane(cidx, j + 0);
            int s1 = __builtin_amdgcn_readlane(cidx, j + 1);
            int s2 = __builtin_amdgcn_readlane(cidx, j + 2);
            int s3 = __builtin_amdgcn_readlane(cidx, j + 3);
            float v0 = h_in[s0 * 64 + lane];
            float v1 = h_in[s1 * 64 + lane];
            float v2 = h_in[s2 * 64 + lane];
            float v3 = h_in[s3 * 64 + lane];
            sum0 += v0; sum1 += v1; sum2 += v2; sum3 += v3;
        }
        for (; j < dgc; ++j) {
            int s0 = __builtin_amdgcn_readlane(cidx, j);
            sum0 += h_in[s0 * 64 + lane];
        }
        for (int k = 64; k < dg; ++k) {        // tail (deg>64: vanishingly rare)
            int s0 = col[rs + k];
            sum0 += h_in[s0 * 64 + lane];
        }
        float sum = (sum0 + sum1) + (sum2 + sum3);
        float mean = sum / fmaxf((float)dg, 1.0f);

        // transform: 4 independent accumulator chains
        float acc0 = bsh[lane], acc1 = 0.f, acc2 = 0.f, acc3 = 0.f;
#pragma unroll
        for (int d = 0; d < HID; d += 4) {
            float2 w0 = w[(d + 0) * 64 + lane];
            float2 w1 = w[(d + 1) * 64 + lane];
            float2 w2 = w[(d + 2) * 64 + lane];
            float2 w3 = w[(d + 3) * 64 + lane];
            float m0 = BCAST(mean, d + 0), s0 = BCAST(self, d + 0);
            float m1 = BCAST(mean, d + 1), s1 = BCAST(self, d + 1);
            float m2 = BCAST(mean, d + 2), s2 = BCAST(self, d + 2);
            float m3 = BCAST(mean, d + 3), s3 = BCAST(self, d + 3);
            acc0 += m0 * w0.x + s0 * w0.y;
            acc1 += m1 * w1.x + s1 * w1.y;
            acc2 += m2 * w2.x + s2 * w2.y;
            acc3 += m3 * w3.x + s3 * w3.y;
        }
        float acc = fmaxf((acc0 + acc1) + (acc2 + acc3), 0.f);   // relu
        h_out[node * 64 + lane] = acc;
    }
}

// ---------------- mean pool + output matmul (one wave per graph) ---------
__global__ __launch_bounds__(256) void pool_kernel(
    const float* __restrict__ h, const int* __restrict__ gstart,
    const float* __restrict__ Wout, const float* __restrict__ bout,
    float* __restrict__ out)
{
    int t = threadIdx.x;
    int wave = t >> 6;
    int lane = t & 63;
    int g = blockIdx.x * 4 + wave;
    if (g >= N_GRAPHS) return;
    int s = gstart[g], e = gstart[g + 1];
    float sum0 = 0.f, sum1 = 0.f, sum2 = 0.f, sum3 = 0.f;
    int i = s;
    for (; i + 4 <= e; i += 4) {
        sum0 += h[(i + 0) * 64 + lane];
        sum1 += h[(i + 1) * 64 + lane];
        sum2 += h[(i + 2) * 64 + lane];
        sum3 += h[(i + 3) * 64 + lane];
    }
    for (; i < e; ++i) sum0 += h[i * 64 + lane];
    float sum = (sum0 + sum1) + (sum2 + sum3);
    float pooled = sum / fmaxf((float)(e - s), 1.0f);
    float r0 = pooled * Wout[lane * 2 + 0];
    float r1 = pooled * Wout[lane * 2 + 1];
#pragma unroll
    for (int off = 32; off > 0; off >>= 1) {
        r0 += __shfl_down(r0, off, 64);
        r1 += __shfl_down(r1, off, 64);
    }
    if (lane == 0) {
        out[g * 2 + 0] = r0 + bout[0];
        out[g * 2 + 1] = r1 + bout[1];
    }
}

extern "C" void kernel_launch(void* const* d_in, const int* in_sizes, int n_in,
                              void* d_out, int out_size, void* d_ws, size_t ws_size,
                              hipStream_t stream) {
    const int*   x    = (const int*)  d_in[0];
    const int*   ei   = (const int*)  d_in[1];   // [2, E] flat
    const int*   batch= (const int*)  d_in[2];
    const float* emb  = (const float*)d_in[3];
    const float* W1l  = (const float*)d_in[4];
    const float* b1   = (const float*)d_in[5];
    const float* W1r  = (const float*)d_in[6];
    const float* W2l  = (const float*)d_in[7];
    const float* b2   = (const float*)d_in[8];
    const float* W2r  = (const float*)d_in[9];
    const float* Wout = (const float*)d_in[10];
    const float* bout = (const float*)d_in[11];
    float* out = (float*)d_out;

    const int* src = ei;
    const int* dst = ei + N_EDGES;

    // workspace layout
    char* ws = (char*)d_ws;
    size_t off = 0;
    float* hA       = (float*)(ws + off); off += (size_t)N_NODES * 64 * 4;   // 25.6 MB
    float* hB       = (float*)(ws + off); off += (size_t)N_NODES * 64 * 4;   // 25.6 MB
    int*   deg      = (int*)  (ws + off); off += (size_t)N_NODES * 4;
    int*   rowst    = (int*)  (ws + off); off += (size_t)N_NODES * 4;
    int*   cursor   = (int*)  (ws + off); off += (size_t)N_NODES * 4;
    int*   col      = (int*)  (ws + off); off += (size_t)N_EDGES * 4;
    int*   gstart   = (int*)  (ws + off); off += (size_t)(N_GRAPHS + 1) * 4;
    int*   total    = (int*)  (ws + off); off += 16;

    // zero what must be zero (ws is poisoned 0xAA before every call)
    hipMemsetAsync(deg, 0, (size_t)N_NODES * 4, stream);
    hipMemsetAsync(total, 0, 16, stream);

    // embed
    embed_kernel<<<(N_NODES * 16 + 255) / 256, 256, 0, stream>>>(x, emb, hA);
    // CSR build (+ graph boundaries fused into base_kernel)
    deg_kernel<<<(N_EDGES + 255) / 256, 256, 0, stream>>>(dst, deg);
    base_kernel<<<(N_NODES + 255) / 256, 256, 0, stream>>>(deg, rowst, cursor, total, batch, gstart);
    fill_kernel<<<(N_EDGES + 255) / 256, 256, 0, stream>>>(src, dst, cursor, col);
    // layer 1: hA -> hB
    sage_layer<<<(N_NODES + NODES_PER_BLOCK - 1) / NODES_PER_BLOCK, 256, 0, stream>>>(
        hA, hB, rowst, deg, col, W1l, W1r, b1);
    // layer 2: hB -> hA
    sage_layer<<<(N_NODES + NODES_PER_BLOCK - 1) / NODES_PER_BLOCK, 256, 0, stream>>>(
        hB, hA, rowst, deg, col, W2l, W2r, b2);
    // pool + classify
    pool_kernel<<<(N_GRAPHS + 3) / 4, 256, 0, stream>>>(hA, gstart, Wout, bout, out);
}

// Round 3
// 419.825 us; speedup vs baseline: 1.8129x; 1.0595x over previous
//
#include <hip/hip_runtime.h>
#include <hip/hip_bf16.h>

#define N_NODES 100000
#define N_EDGES 1000000
#define EMB 64
#define HID 64
#define VOCAB 128
#define N_GRAPHS 2048

#define BCASTF(v, l) __int_as_float(__builtin_amdgcn_readlane(__float_as_int(v), (l)))

// ---- precompute embW1l = emb @ W1l, embW1r = emb @ W1r  (128x64 each) ----
__global__ __launch_bounds__(256) void precompute_kernel(
    const float* __restrict__ emb, const float* __restrict__ W1l,
    const float* __restrict__ W1r,
    float* __restrict__ embW1l, float* __restrict__ embW1r)
{
    int wave = threadIdx.x >> 6, lane = threadIdx.x & 63;
    int v = blockIdx.x * 4 + wave;
    if (v >= VOCAB) return;
    float er = emb[v * 64 + lane];       // lane = d
    float al = 0.f, ar = 0.f;
#pragma unroll 8
    for (int d = 0; d < 64; ++d) {
        float e = BCASTF(er, d);
        al += e * W1l[d * 64 + lane];    // lane = o, L1-hot
        ar += e * W1r[d * 64 + lane];
    }
    embW1l[v * 64 + lane] = al;
    embW1r[v * 64 + lane] = ar;
}

// ---------------- degree histogram ----------------
__global__ __launch_bounds__(256) void deg_kernel(
    const int* __restrict__ dst, int* __restrict__ deg)
{
    int e = blockIdx.x * 256 + threadIdx.x;
    if (e < N_EDGES) atomicAdd(&deg[dst[e]], 1);
}

// ------- block-scan bases (order-free CSR base assignment) + gstart ------
__global__ __launch_bounds__(256) void base_kernel(
    const int* __restrict__ deg, int* __restrict__ row_start,
    int* __restrict__ cursor, int* __restrict__ total,
    const int* __restrict__ batch, int* __restrict__ gstart)
{
    __shared__ int sdata[256];
    __shared__ int sbase;
    int t = threadIdx.x;
    int i = blockIdx.x * 256 + t;
    int v = (i < N_NODES) ? deg[i] : 0;
    sdata[t] = v;
    __syncthreads();
    for (int off = 1; off < 256; off <<= 1) {
        int tmp = (t >= off) ? sdata[t - off] : 0;
        __syncthreads();
        sdata[t] += tmp;
        __syncthreads();
    }
    if (t == 255) sbase = atomicAdd(total, sdata[255]);
    __syncthreads();
    if (i < N_NODES) {
        int b = sbase + sdata[t] - v;
        row_start[i] = b;
        cursor[i] = b;
        int bg = batch[i];
        int bp = (i == 0) ? -1 : batch[i - 1];
        for (int g = bp + 1; g <= bg; ++g) gstart[g] = i;
        if (i == N_NODES - 1)
            for (int g = bg + 1; g <= N_GRAPHS; ++g) gstart[g] = N_NODES;
    }
}

// ---------------- CSR fill ----------------
__global__ __launch_bounds__(256) void fill_kernel(
    const int* __restrict__ src, const int* __restrict__ dst,
    int* __restrict__ cursor, int* __restrict__ col)
{
    int e = blockIdx.x * 256 + threadIdx.x;
    if (e < N_EDGES) {
        int p = atomicAdd(&cursor[dst[e]], 1);
        col[p] = src[e];
    }
}

// ---- layer 1: h1 = relu(mean_j(embW1l[x_j]) + b1 + embW1r[x_i]) ----
// All feature gathers served from a 32 KB LDS copy of embW1l.
#define S1_NPW 8
__global__ __launch_bounds__(256) void sage1_kernel(
    const int* __restrict__ x, const float* __restrict__ embW1l,
    const float* __restrict__ embW1r, const float* __restrict__ b1,
    const int* __restrict__ row_start, const int* __restrict__ deg,
    const int* __restrict__ col, float* __restrict__ h1)
{
    __shared__ float elds[VOCAB * 64];   // 32 KB
    int t = threadIdx.x;
    for (int i = t * 4; i < VOCAB * 64; i += 1024)
        *(float4*)&elds[i] = *(const float4*)&embW1l[i];
    __syncthreads();

    int wave = t >> 6, lane = t & 63;
    int base_node = (blockIdx.x * 4 + wave) * S1_NPW;   // 3125*4*8 = 100000 exact
    float bias = b1[lane];

    for (int n = 0; n < S1_NPW; ++n) {
        int node = base_node + n;
        int rs = row_start[node];
        int dg = deg[node];
        int xn = x[node];
        float self = embW1r[xn * 64 + lane];            // 32 KB table, L1-hot
        int cidx = (lane < dg) ? col[rs + lane] : 0;
        int xv = (lane < dg) ? x[cidx] : 0;             // one gather covers all edges
        int dgc = (dg < 64) ? dg : 64;

        float s0 = 0.f, s1 = 0.f, s2 = 0.f, s3 = 0.f;
        int j = 0;
        for (; j + 4 <= dgc; j += 4) {
            int x0 = __builtin_amdgcn_readlane(xv, j + 0);
            int x1 = __builtin_amdgcn_readlane(xv, j + 1);
            int x2 = __builtin_amdgcn_readlane(xv, j + 2);
            int x3 = __builtin_amdgcn_readlane(xv, j + 3);
            s0 += elds[x0 * 64 + lane];
            s1 += elds[x1 * 64 + lane];
            s2 += elds[x2 * 64 + lane];
            s3 += elds[x3 * 64 + lane];
        }
        for (; j < dgc; ++j) {
            int x0 = __builtin_amdgcn_readlane(xv, j);
            s0 += elds[x0 * 64 + lane];
        }
        for (int k = 64; k < dg; ++k) {                 // deg>64 tail (rare)
            int c = col[rs + k];
            s0 += elds[x[c] * 64 + lane];
        }
        float mean = ((s0 + s1) + (s2 + s3)) / fmaxf((float)dg, 1.0f);
        h1[node * 64 + lane] = fmaxf(mean + bias + self, 0.f);
    }
}

// ---- layer 2 + fused pooling-dot:
//   h2 = relu(mean@W2l + b2 + self@W2r);  atomic gsum[g] += h2@Wout ----
#define S2_NPW 8
__global__ __launch_bounds__(256) void sage2_kernel(
    const float* __restrict__ h1,
    const int* __restrict__ row_start, const int* __restrict__ deg,
    const int* __restrict__ col,
    const float* __restrict__ W2l, const float* __restrict__ W2r,
    const float* __restrict__ b2, const float* __restrict__ Wout,
    const int* __restrict__ batch, float* __restrict__ gsum)
{
    __shared__ float2 w[HID * HID];                 // (Wl, Wr) interleaved, 32 KB
    __shared__ float msbuf[4][S2_NPW][2][HID];      // 16 KB wave-private
    int t = threadIdx.x;
    for (int idx = t * 4; idx < HID * HID; idx += 1024) {
        float4 a = *(const float4*)(W2l + idx);
        float4 b = *(const float4*)(W2r + idx);
        w[idx + 0] = make_float2(a.x, b.x);
        w[idx + 1] = make_float2(a.y, b.y);
        w[idx + 2] = make_float2(a.z, b.z);
        w[idx + 3] = make_float2(a.w, b.w);
    }
    __syncthreads();

    int wave = t >> 6, lane = t & 63;
    int base_node = (blockIdx.x * 4 + wave) * S2_NPW;   // exact cover
    float bias = b2[lane];
    float wo0 = Wout[lane * 2 + 0], wo1 = Wout[lane * 2 + 1];

    // prefetch all per-node metadata + neighbor indices + self rows
    int rs[S2_NPW], dgs[S2_NPW], cidx[S2_NPW];
    float self[S2_NPW];
#pragma unroll
    for (int n = 0; n < S2_NPW; ++n) {
        rs[n] = row_start[base_node + n];
        dgs[n] = deg[base_node + n];
    }
#pragma unroll
    for (int n = 0; n < S2_NPW; ++n) {
        cidx[n] = (lane < dgs[n]) ? col[rs[n] + lane] : 0;
        self[n] = h1[(base_node + n) * 64 + lane];
    }

    // gather phase: 8 outstanding loads per node
    for (int n = 0; n < S2_NPW; ++n) {
        int dg = dgs[n];
        int dgc = (dg < 64) ? dg : 64;
        float s0 = 0.f, s1 = 0.f, s2 = 0.f, s3 = 0.f,
              s4 = 0.f, s5 = 0.f, s6 = 0.f, s7 = 0.f;
        int j = 0;
        for (; j + 8 <= dgc; j += 8) {
            int i0 = __builtin_amdgcn_readlane(cidx[n], j + 0);
            int i1 = __builtin_amdgcn_readlane(cidx[n], j + 1);
            int i2 = __builtin_amdgcn_readlane(cidx[n], j + 2);
            int i3 = __builtin_amdgcn_readlane(cidx[n], j + 3);
            int i4 = __builtin_amdgcn_readlane(cidx[n], j + 4);
            int i5 = __builtin_amdgcn_readlane(cidx[n], j + 5);
            int i6 = __builtin_amdgcn_readlane(cidx[n], j + 6);
            int i7 = __builtin_amdgcn_readlane(cidx[n], j + 7);
            s0 += h1[i0 * 64 + lane];  s1 += h1[i1 * 64 + lane];
            s2 += h1[i2 * 64 + lane];  s3 += h1[i3 * 64 + lane];
            s4 += h1[i4 * 64 + lane];  s5 += h1[i5 * 64 + lane];
            s6 += h1[i6 * 64 + lane];  s7 += h1[i7 * 64 + lane];
        }
        for (; j + 4 <= dgc; j += 4) {
            int i0 = __builtin_amdgcn_readlane(cidx[n], j + 0);
            int i1 = __builtin_amdgcn_readlane(cidx[n], j + 1);
            int i2 = __builtin_amdgcn_readlane(cidx[n], j + 2);
            int i3 = __builtin_amdgcn_readlane(cidx[n], j + 3);
            s0 += h1[i0 * 64 + lane];  s1 += h1[i1 * 64 + lane];
            s2 += h1[i2 * 64 + lane];  s3 += h1[i3 * 64 + lane];
        }
        for (; j < dgc; ++j) {
            int i0 = __builtin_amdgcn_readlane(cidx[n], j);
            s0 += h1[i0 * 64 + lane];
        }
        for (int k = 64; k < dgs[n]; ++k)
            s0 += h1[col[rs[n] + k] * 64 + lane];
        float sum = ((s0 + s1) + (s2 + s3)) + ((s4 + s5) + (s6 + s7));
        float mean = sum / fmaxf((float)dg, 1.0f);
        msbuf[wave][n][0][lane] = mean;
        msbuf[wave][n][1][lane] = self[n];
    }
    __builtin_amdgcn_wave_barrier();   // wave-private LDS; DS pipe in-order per wave

    // transform: 8 nodes share each weight chunk; broadcasts via uniform b128
    float acc[S2_NPW];
#pragma unroll
    for (int n = 0; n < S2_NPW; ++n) acc[n] = 0.f;
    for (int d = 0; d < HID; d += 4) {
        float2 w0 = w[(d + 0) * 64 + lane];
        float2 w1 = w[(d + 1) * 64 + lane];
        float2 w2 = w[(d + 2) * 64 + lane];
        float2 w3 = w[(d + 3) * 64 + lane];
#pragma unroll
        for (int n = 0; n < S2_NPW; ++n) {
            float4 m4 = *(const float4*)&msbuf[wave][n][0][d];   // uniform read
            float4 s4 = *(const float4*)&msbuf[wave][n][1][d];
            acc[n] += m4.x * w0.x + s4.x * w0.y;
            acc[n] += m4.y * w1.x + s4.y * w1.y;
            acc[n] += m4.z * w2.x + s4.z * w2.y;
            acc[n] += m4.w * w3.x + s4.w * w3.y;
        }
    }

    // epilogue: relu, dot with Wout columns, reduce, atomic into graph sums
#pragma unroll
    for (int n = 0; n < S2_NPW; ++n) {
        float h2 = fmaxf(acc[n] + bias, 0.f);
        float p0 = h2 * wo0, p1 = h2 * wo1;
#pragma unroll
        for (int off = 32; off > 0; off >>= 1) {
            p0 += __shfl_down(p0, off, 64);
            p1 += __shfl_down(p1, off, 64);
        }
        if (lane == 0) {
            int g = batch[base_node + n];
            atomicAdd(&gsum[g * 2 + 0], p0);
            atomicAdd(&gsum[g * 2 + 1], p1);
        }
    }
}

// ---------------- finalize: out = gsum/cnt + bout ----------------
__global__ __launch_bounds__(256) void finalize_kernel(
    const float* __restrict__ gsum, const int* __restrict__ gstart,
    const float* __restrict__ bout, float* __restrict__ out)
{
    int g = blockIdx.x * 256 + threadIdx.x;
    if (g >= N_GRAPHS) return;
    int cnt = gstart[g + 1] - gstart[g];
    float inv = 1.0f / fmaxf((float)cnt, 1.0f);
    out[g * 2 + 0] = gsum[g * 2 + 0] * inv + bout[0];
    out[g * 2 + 1] = gsum[g * 2 + 1] * inv + bout[1];
}

extern "C" void kernel_launch(void* const* d_in, const int* in_sizes, int n_in,
                              void* d_out, int out_size, void* d_ws, size_t ws_size,
                              hipStream_t stream) {
    const int*   x    = (const int*)  d_in[0];
    const int*   ei   = (const int*)  d_in[1];
    const int*   batch= (const int*)  d_in[2];
    const float* emb  = (const float*)d_in[3];
    const float* W1l  = (const float*)d_in[4];
    const float* b1   = (const float*)d_in[5];
    const float* W1r  = (const float*)d_in[6];
    const float* W2l  = (const float*)d_in[7];
    const float* b2   = (const float*)d_in[8];
    const float* W2r  = (const float*)d_in[9];
    const float* Wout = (const float*)d_in[10];
    const float* bout = (const float*)d_in[11];
    float* out = (float*)d_out;

    const int* src = ei;
    const int* dst = ei + N_EDGES;

    char* ws = (char*)d_ws;
    size_t off = 0;
    float* h1     = (float*)(ws + off); off += (size_t)N_NODES * 64 * 4;   // 25.6 MB
    float* embW1l = (float*)(ws + off); off += (size_t)VOCAB * 64 * 4;
    float* embW1r = (float*)(ws + off); off += (size_t)VOCAB * 64 * 4;
    int*   rowst  = (int*)  (ws + off); off += (size_t)N_NODES * 4;
    int*   cursor = (int*)  (ws + off); off += (size_t)N_NODES * 4;
    int*   col    = (int*)  (ws + off); off += (size_t)N_EDGES * 4;
    int*   gstart = (int*)  (ws + off); off += (size_t)(N_GRAPHS + 1) * 4;
    // contiguous zero region: deg | total | gsum
    int*   deg    = (int*)  (ws + off); off += (size_t)N_NODES * 4;
    int*   total  = (int*)  (ws + off); off += 16;
    float* gsum   = (float*)(ws + off); off += (size_t)N_GRAPHS * 2 * 4;

    hipMemsetAsync(deg, 0, (size_t)N_NODES * 4 + 16 + (size_t)N_GRAPHS * 2 * 4, stream);

    precompute_kernel<<<32, 256, 0, stream>>>(emb, W1l, W1r, embW1l, embW1r);
    deg_kernel<<<(N_EDGES + 255) / 256, 256, 0, stream>>>(dst, deg);
    base_kernel<<<(N_NODES + 255) / 256, 256, 0, stream>>>(deg, rowst, cursor, total, batch, gstart);
    fill_kernel<<<(N_EDGES + 255) / 256, 256, 0, stream>>>(src, dst, cursor, col);
    sage1_kernel<<<N_NODES / (4 * S1_NPW), 256, 0, stream>>>(   // 3125 blocks, exact
        x, embW1l, embW1r, b1, rowst, deg, col, h1);
    sage2_kernel<<<N_NODES / (4 * S2_NPW), 256, 0, stream>>>(   // 3125 blocks, exact
        h1, rowst, deg, col, W2l, W2r, b2, Wout, batch, gsum);
    finalize_kernel<<<(N_GRAPHS + 255) / 256, 256, 0, stream>>>(gsum, gstart, bout, out);
}

// Round 4
// 343.176 us; speedup vs baseline: 2.2178x; 1.2234x over previous
//
#include <hip/hip_runtime.h>
#include <hip/hip_bf16.h>

#define N_NODES 100000
#define N_EDGES 1000000
#define EMB 64
#define HID 64
#define VOCAB 128
#define N_GRAPHS 2048

#define BCASTF(v, l) __int_as_float(__builtin_amdgcn_readlane(__float_as_int(v), (l)))

// ---- precompute embW1l = emb @ W1l, embW1r = emb @ W1r  (128x64 each) ----
__global__ __launch_bounds__(256) void precompute_kernel(
    const float* __restrict__ emb, const float* __restrict__ W1l,
    const float* __restrict__ W1r,
    float* __restrict__ embW1l, float* __restrict__ embW1r)
{
    int wave = threadIdx.x >> 6, lane = threadIdx.x & 63;
    int v = blockIdx.x * 4 + wave;
    if (v >= VOCAB) return;
    float er = emb[v * 64 + lane];       // lane = d
    float al = 0.f, ar = 0.f;
#pragma unroll 8
    for (int d = 0; d < 64; ++d) {
        float e = BCASTF(er, d);
        al += e * W1l[d * 64 + lane];    // lane = o, L1-hot
        ar += e * W1r[d * 64 + lane];
    }
    embW1l[v * 64 + lane] = al;
    embW1r[v * 64 + lane] = ar;
}

// ---------------- degree histogram ----------------
__global__ __launch_bounds__(256) void deg_kernel(
    const int* __restrict__ dst, int* __restrict__ deg)
{
    int e = blockIdx.x * 256 + threadIdx.x;
    if (e < N_EDGES) atomicAdd(&deg[dst[e]], 1);
}

// ------- block-scan bases (order-free CSR base assignment) + gstart ------
__global__ __launch_bounds__(256) void base_kernel(
    const int* __restrict__ deg, int* __restrict__ row_start,
    int* __restrict__ cursor, int* __restrict__ total,
    const int* __restrict__ batch, int* __restrict__ gstart)
{
    __shared__ int sdata[256];
    __shared__ int sbase;
    int t = threadIdx.x;
    int i = blockIdx.x * 256 + t;
    int v = (i < N_NODES) ? deg[i] : 0;
    sdata[t] = v;
    __syncthreads();
    for (int off = 1; off < 256; off <<= 1) {
        int tmp = (t >= off) ? sdata[t - off] : 0;
        __syncthreads();
        sdata[t] += tmp;
        __syncthreads();
    }
    if (t == 255) sbase = atomicAdd(total, sdata[255]);
    __syncthreads();
    if (i < N_NODES) {
        int b = sbase + sdata[t] - v;
        row_start[i] = b;
        cursor[i] = b;
        int bg = batch[i];
        int bp = (i == 0) ? -1 : batch[i - 1];
        for (int g = bp + 1; g <= bg; ++g) gstart[g] = i;
        if (i == N_NODES - 1)
            for (int g = bg + 1; g <= N_GRAPHS; ++g) gstart[g] = N_NODES;
    }
}

// ---------------- CSR fill ----------------
__global__ __launch_bounds__(256) void fill_kernel(
    const int* __restrict__ src, const int* __restrict__ dst,
    int* __restrict__ cursor, int* __restrict__ col)
{
    int e = blockIdx.x * 256 + threadIdx.x;
    if (e < N_EDGES) {
        int p = atomicAdd(&cursor[dst[e]], 1);
        col[p] = src[e];
    }
}

// ---- layer 1: h1 = relu(mean_j(embW1l[x_j]) + b1 + embW1r[x_i]) ----
#define S1_NPW 8
__global__ __launch_bounds__(256) void sage1_kernel(
    const int* __restrict__ x, const float* __restrict__ embW1l,
    const float* __restrict__ embW1r, const float* __restrict__ b1,
    const int* __restrict__ row_start, const int* __restrict__ deg,
    const int* __restrict__ col, float* __restrict__ h1)
{
    __shared__ float elds[VOCAB * 64];   // 32 KB
    int t = threadIdx.x;
    for (int i = t * 4; i < VOCAB * 64; i += 1024)
        *(float4*)&elds[i] = *(const float4*)&embW1l[i];
    __syncthreads();

    int wave = t >> 6, lane = t & 63;
    int base_node = (blockIdx.x * 4 + wave) * S1_NPW;   // 3125*4*8 = 100000 exact
    float bias = b1[lane];

    for (int n = 0; n < S1_NPW; ++n) {
        int node = base_node + n;
        int rs = row_start[node];
        int dg = deg[node];
        int xn = x[node];
        float self = embW1r[xn * 64 + lane];            // 32 KB table, L1-hot
        int cidx = (lane < dg) ? col[rs + lane] : 0;
        int xv = (lane < dg) ? x[cidx] : 0;
        int dgc = (dg < 64) ? dg : 64;

        float s0 = 0.f, s1 = 0.f, s2 = 0.f, s3 = 0.f;
        int j = 0;
        for (; j + 4 <= dgc; j += 4) {
            int x0 = __builtin_amdgcn_readlane(xv, j + 0);
            int x1 = __builtin_amdgcn_readlane(xv, j + 1);
            int x2 = __builtin_amdgcn_readlane(xv, j + 2);
            int x3 = __builtin_amdgcn_readlane(xv, j + 3);
            s0 += elds[x0 * 64 + lane];
            s1 += elds[x1 * 64 + lane];
            s2 += elds[x2 * 64 + lane];
            s3 += elds[x3 * 64 + lane];
        }
        for (; j < dgc; ++j) {
            int x0 = __builtin_amdgcn_readlane(xv, j);
            s0 += elds[x0 * 64 + lane];
        }
        for (int k = 64; k < dg; ++k) {
            int c = col[rs + k];
            s0 += elds[x[c] * 64 + lane];
        }
        float mean = ((s0 + s1) + (s2 + s3)) / fmaxf((float)dg, 1.0f);
        h1[node * 64 + lane] = fmaxf(mean + bias + self, 0.f);
    }
}

// ---- dense transform: p = h1 @ W2l (in place over h1), q = h1 @ W2r ----
#define T_NPW 8
__global__ __launch_bounds__(256) void transform_kernel(
    float* __restrict__ h1p,            // in: h1, out: p (row-exact alias)
    const float* __restrict__ W2l, const float* __restrict__ W2r,
    float* __restrict__ q)
{
    __shared__ float2 w[HID * HID];     // (Wl[d][o], Wr[d][o]) interleaved, 32 KB
    __shared__ float ms[4][T_NPW][HID]; // 8 KB wave-private
    int t = threadIdx.x;
    for (int idx = t * 4; idx < HID * HID; idx += 1024) {
        float4 a = *(const float4*)(W2l + idx);
        float4 b = *(const float4*)(W2r + idx);
        w[idx + 0] = make_float2(a.x, b.x);
        w[idx + 1] = make_float2(a.y, b.y);
        w[idx + 2] = make_float2(a.z, b.z);
        w[idx + 3] = make_float2(a.w, b.w);
    }
    __syncthreads();

    int wave = t >> 6, lane = t & 63;
    int base_node = (blockIdx.x * 4 + wave) * T_NPW;    // exact cover

    // stage all 8 h1 rows into wave-private LDS before any write-back
#pragma unroll
    for (int n = 0; n < T_NPW; ++n)
        ms[wave][n][lane] = h1p[(base_node + n) * 64 + lane];
    __builtin_amdgcn_wave_barrier();    // wave-private LDS; DS in-order per wave

    float accp[T_NPW], accq[T_NPW];
#pragma unroll
    for (int n = 0; n < T_NPW; ++n) { accp[n] = 0.f; accq[n] = 0.f; }

#pragma unroll 4
    for (int d = 0; d < HID; d += 4) {
        float2 w0 = w[(d + 0) * 64 + lane];
        float2 w1 = w[(d + 1) * 64 + lane];
        float2 w2 = w[(d + 2) * 64 + lane];
        float2 w3 = w[(d + 3) * 64 + lane];
#pragma unroll
        for (int n = 0; n < T_NPW; ++n) {
            float4 m = *(const float4*)&ms[wave][n][d];   // uniform broadcast
            accp[n] += m.x * w0.x + m.y * w1.x + m.z * w2.x + m.w * w3.x;
            accq[n] += m.x * w0.y + m.y * w1.y + m.z * w2.y + m.w * w3.y;
        }
    }
#pragma unroll
    for (int n = 0; n < T_NPW; ++n) {
        h1p[(base_node + n) * 64 + lane] = accp[n];   // p overwrites h1
        q[(base_node + n) * 64 + lane]   = accq[n];
    }
}

// ---- lean gather: h2 = relu(mean_j p_j + b2 + q_i); gsum[g] += h2@Wout ----
// zero weight-LDS, VGPR-capped for max occupancy; 8-deep gather ILP
#define S2_NPW 8
__global__ __launch_bounds__(256, 8) void sage2_kernel(
    const float* __restrict__ p, const float* __restrict__ q,
    const int* __restrict__ row_start, const int* __restrict__ deg,
    const int* __restrict__ col, const float* __restrict__ b2,
    const float* __restrict__ Wout, const int* __restrict__ batch,
    float* __restrict__ gsum)
{
    int t = threadIdx.x;
    int wave = t >> 6, lane = t & 63;
    int base_node = (blockIdx.x * 4 + wave) * S2_NPW;   // exact cover
    float bias = b2[lane];
    float wo0 = Wout[lane * 2 + 0], wo1 = Wout[lane * 2 + 1];

    for (int n = 0; n < S2_NPW; ++n) {
        int node = base_node + n;
        int rs = row_start[node];       // wave-uniform -> scalar
        int dg = deg[node];
        int cidx = (lane < dg) ? col[rs + lane] : 0;
        int dgc = (dg < 64) ? dg : 64;

        float s0 = 0.f, s1 = 0.f, s2 = 0.f, s3 = 0.f,
              s4 = 0.f, s5 = 0.f, s6 = 0.f, s7 = 0.f;
        int j = 0;
        for (; j + 8 <= dgc; j += 8) {
            int i0 = __builtin_amdgcn_readlane(cidx, j + 0);
            int i1 = __builtin_amdgcn_readlane(cidx, j + 1);
            int i2 = __builtin_amdgcn_readlane(cidx, j + 2);
            int i3 = __builtin_amdgcn_readlane(cidx, j + 3);
            int i4 = __builtin_amdgcn_readlane(cidx, j + 4);
            int i5 = __builtin_amdgcn_readlane(cidx, j + 5);
            int i6 = __builtin_amdgcn_readlane(cidx, j + 6);
            int i7 = __builtin_amdgcn_readlane(cidx, j + 7);
            s0 += p[i0 * 64 + lane];  s1 += p[i1 * 64 + lane];
            s2 += p[i2 * 64 + lane];  s3 += p[i3 * 64 + lane];
            s4 += p[i4 * 64 + lane];  s5 += p[i5 * 64 + lane];
            s6 += p[i6 * 64 + lane];  s7 += p[i7 * 64 + lane];
        }
        for (; j + 4 <= dgc; j += 4) {
            int i0 = __builtin_amdgcn_readlane(cidx, j + 0);
            int i1 = __builtin_amdgcn_readlane(cidx, j + 1);
            int i2 = __builtin_amdgcn_readlane(cidx, j + 2);
            int i3 = __builtin_amdgcn_readlane(cidx, j + 3);
            s0 += p[i0 * 64 + lane];  s1 += p[i1 * 64 + lane];
            s2 += p[i2 * 64 + lane];  s3 += p[i3 * 64 + lane];
        }
        for (; j < dgc; ++j) {
            int i0 = __builtin_amdgcn_readlane(cidx, j);
            s0 += p[i0 * 64 + lane];
        }
        for (int k = 64; k < dg; ++k)
            s0 += p[col[rs + k] * 64 + lane];

        float sum = ((s0 + s1) + (s2 + s3)) + ((s4 + s5) + (s6 + s7));
        float mean = sum / fmaxf((float)dg, 1.0f);
        float h2 = fmaxf(mean + bias + q[node * 64 + lane], 0.f);

        float p0 = h2 * wo0, p1 = h2 * wo1;
#pragma unroll
        for (int off = 32; off > 0; off >>= 1) {
            p0 += __shfl_down(p0, off, 64);
            p1 += __shfl_down(p1, off, 64);
        }
        if (lane == 0) {
            int g = batch[node];
            atomicAdd(&gsum[g * 2 + 0], p0);
            atomicAdd(&gsum[g * 2 + 1], p1);
        }
    }
}

// ---------------- finalize: out = gsum/cnt + bout ----------------
__global__ __launch_bounds__(256) void finalize_kernel(
    const float* __restrict__ gsum, const int* __restrict__ gstart,
    const float* __restrict__ bout, float* __restrict__ out)
{
    int g = blockIdx.x * 256 + threadIdx.x;
    if (g >= N_GRAPHS) return;
    int cnt = gstart[g + 1] - gstart[g];
    float inv = 1.0f / fmaxf((float)cnt, 1.0f);
    out[g * 2 + 0] = gsum[g * 2 + 0] * inv + bout[0];
    out[g * 2 + 1] = gsum[g * 2 + 1] * inv + bout[1];
}

extern "C" void kernel_launch(void* const* d_in, const int* in_sizes, int n_in,
                              void* d_out, int out_size, void* d_ws, size_t ws_size,
                              hipStream_t stream) {
    const int*   x    = (const int*)  d_in[0];
    const int*   ei   = (const int*)  d_in[1];
    const int*   batch= (const int*)  d_in[2];
    const float* emb  = (const float*)d_in[3];
    const float* W1l  = (const float*)d_in[4];
    const float* b1   = (const float*)d_in[5];
    const float* W1r  = (const float*)d_in[6];
    const float* W2l  = (const float*)d_in[7];
    const float* b2   = (const float*)d_in[8];
    const float* W2r  = (const float*)d_in[9];
    const float* Wout = (const float*)d_in[10];
    const float* bout = (const float*)d_in[11];
    float* out = (float*)d_out;

    const int* src = ei;
    const int* dst = ei + N_EDGES;

    char* ws = (char*)d_ws;
    size_t off = 0;
    float* h1p    = (float*)(ws + off); off += (size_t)N_NODES * 64 * 4;   // h1 then p
    float* q      = (float*)(ws + off); off += (size_t)N_NODES * 64 * 4;
    float* embW1l = (float*)(ws + off); off += (size_t)VOCAB * 64 * 4;
    float* embW1r = (float*)(ws + off); off += (size_t)VOCAB * 64 * 4;
    int*   rowst  = (int*)  (ws + off); off += (size_t)N_NODES * 4;
    int*   cursor = (int*)  (ws + off); off += (size_t)N_NODES * 4;
    int*   col    = (int*)  (ws + off); off += (size_t)N_EDGES * 4;
    int*   gstart = (int*)  (ws + off); off += (size_t)(N_GRAPHS + 1) * 4;
    // contiguous zero region: deg | total | gsum
    int*   deg    = (int*)  (ws + off); off += (size_t)N_NODES * 4;
    int*   total  = (int*)  (ws + off); off += 16;
    float* gsum   = (float*)(ws + off); off += (size_t)N_GRAPHS * 2 * 4;

    hipMemsetAsync(deg, 0, (size_t)N_NODES * 4 + 16 + (size_t)N_GRAPHS * 2 * 4, stream);

    precompute_kernel<<<32, 256, 0, stream>>>(emb, W1l, W1r, embW1l, embW1r);
    deg_kernel<<<(N_EDGES + 255) / 256, 256, 0, stream>>>(dst, deg);
    base_kernel<<<(N_NODES + 255) / 256, 256, 0, stream>>>(deg, rowst, cursor, total, batch, gstart);
    fill_kernel<<<(N_EDGES + 255) / 256, 256, 0, stream>>>(src, dst, cursor, col);
    sage1_kernel<<<N_NODES / (4 * S1_NPW), 256, 0, stream>>>(
        x, embW1l, embW1r, b1, rowst, deg, col, h1p);
    transform_kernel<<<N_NODES / (4 * T_NPW), 256, 0, stream>>>(h1p, W2l, W2r, q);
    sage2_kernel<<<N_NODES / (4 * S2_NPW), 256, 0, stream>>>(
        h1p, q, rowst, deg, col, b2, Wout, batch, gsum);
    finalize_kernel<<<(N_GRAPHS + 255) / 256, 256, 0, stream>>>(gsum, gstart, bout, out);
}